// Round 23
// baseline (232.582 us; speedup 1.0000x reference)
//
#include <hip/hip_runtime.h>
#include <math.h>

typedef unsigned long long u64;

#define N_PTS 16384
#define HALF_N 8192
#define KK 16
#define NK (N_PTS * KK)
#define EPSV 1e-5f
#define FINF 0x7f800000u

// ---- KNN tau phase: 32 groups x 64 candidates (subset 2048 per query) ----
#define TGRP 32                  // groups per query
#define TGC 64                   // candidates per group
// ---- KNN collect phase: 2 queries per wave, 8 candidates per lane ----
#define QW 2                     // queries per wave
#define QBLK 8                   // queries per 256-thread block
#define CAP 288                  // accept capacity (E~88, huge margin)

// ---- workspace layout (bytes) ----
#define OFF_IDX   0u                           // int32 [N_PTS][KK]         = 1 MB
#define OFF_PC    (1u << 20)                   // float4 [N_PTS]            = 256 KB
#define OFF_MA    (OFF_PC + N_PTS * 16u)       // m0 / m3 low / gsubT
#define OFF_MB    (OFF_MA + N_PTS * 16u * 4u)  // m1 / m3 high / gsubT
#define OFF_MC    (OFF_MB + N_PTS * 16u * 4u)  // m2 [N][32]                = 2 MB
#define OFF_PART  (OFF_MC + N_PTS * 32u * 4u)  // part [1024][64] / tauArr  = 256 KB
#define OFF_STATS (OFF_PART + 1024u * 64u * 4u)// float [4][64]
// gsubT (f32 [TGRP][N_PTS] = 2 MB) overlays MA|MB (dead during KNN)
// tauArr (f32 [N_PTS] = 64 KB) overlays OFF_PART (dead until conv phase)

// ---------------- prep: pack (x,y,z,d2) ----------------
__global__ __launch_bounds__(256) void prep_kernel(const float* __restrict__ pts,
                                                   float4* __restrict__ pc) {
    int i = blockIdx.x * 256 + threadIdx.x;
    float x = pts[i * 5 + 1], y = pts[i * 5 + 2], z = pts[i * 5 + 3];
    float d2 = __fadd_rn(__fadd_rn(__fmul_rn(x, x), __fmul_rn(y, y)), __fmul_rn(z, z));
    pc[i] = make_float4(x, y, z, d2);
}

// monotone key transform (float bits -> sortable uint)
__device__ __forceinline__ unsigned fkey(unsigned u) {
    return u ^ ((unsigned)(((int)u) >> 31) | 0x80000000u);
}

__device__ __forceinline__ void cef32(float& a, float& b) {
    float t = fminf(a, b);
    b = fmaxf(a, b);
    a = t;
}

// sort 8 ascending f32 (Batcher, 19 CE)
__device__ __forceinline__ void sort8f(float* b) {
    cef32(b[0], b[1]); cef32(b[2], b[3]); cef32(b[4], b[5]); cef32(b[6], b[7]);
    cef32(b[0], b[2]); cef32(b[1], b[3]); cef32(b[4], b[6]); cef32(b[5], b[7]);
    cef32(b[1], b[2]); cef32(b[5], b[6]);
    cef32(b[0], b[4]); cef32(b[1], b[5]); cef32(b[2], b[6]); cef32(b[3], b[7]);
    cef32(b[2], b[4]); cef32(b[3], b[5]);
    cef32(b[1], b[2]); cef32(b[3], b[4]); cef32(b[5], b[6]);
}

// sort 16 ascending f32: two sort8 + bitonic merge
__device__ __forceinline__ void sort16f(float b[16]) {
    sort8f(b); sort8f(b + 8);
#pragma unroll
    for (int j = 0; j < 8; ++j) cef32(b[j], b[15 - j]);
#pragma unroll
    for (int h = 0; h < 16; h += 8) {
        cef32(b[h + 0], b[h + 4]); cef32(b[h + 1], b[h + 5]);
        cef32(b[h + 2], b[h + 6]); cef32(b[h + 3], b[h + 7]);
        cef32(b[h + 0], b[h + 2]); cef32(b[h + 1], b[h + 3]);
        cef32(b[h + 4], b[h + 6]); cef32(b[h + 5], b[h + 7]);
        cef32(b[h + 0], b[h + 1]); cef32(b[h + 2], b[h + 3]);
        cef32(b[h + 4], b[h + 5]); cef32(b[h + 6], b[h + 7]);
    }
}

// ======== TAU1 v2: per (query, group) min over 64 candidates ========
// 2 block-uniform candidate loads in flight per iteration; fixed-order fmin
// chain (exact min -> bit-identical).
__global__ __launch_bounds__(256, 8) void tau1_kernel(const float4* __restrict__ pc,
                                                      float* __restrict__ gsubT) {
    const int qb = blockIdx.x >> 5;          // query block 0..63
    const int g  = blockIdx.x & (TGRP - 1);  // group 0..31
    const int n  = qb * 256 + threadIdx.x;
    const int base = (n >= HALF_N) ? HALF_N : 0;
    const float4 p = pc[n];

    float m = __uint_as_float(FINF);
    const int c0 = base + g * TGC; // subset = first 2048 of the batch half
#pragma unroll 4
    for (int t = 0; t < TGC; t += 2) {
        const float4 cp0 = pc[c0 + t];     // block-uniform -> broadcast, L1-hot
        const float4 cp1 = pc[c0 + t + 1]; // second load in flight
        float dot0 = __fadd_rn(__fadd_rn(__fmul_rn(p.x, cp0.x), __fmul_rn(p.y, cp0.y)),
                               __fmul_rn(p.z, cp0.z));
        float d0 = __fsub_rn(__fadd_rn(p.w, cp0.w), __fmul_rn(2.0f, dot0));
        float dot1 = __fadd_rn(__fadd_rn(__fmul_rn(p.x, cp1.x), __fmul_rn(p.y, cp1.y)),
                               __fmul_rn(p.z, cp1.z));
        float d1 = __fsub_rn(__fadd_rn(p.w, cp1.w), __fmul_rn(2.0f, dot1));
        m = fminf(fminf(m, d0), d1); // fixed order; min is exact
    }
    gsubT[g * N_PTS + n] = m; // lane-consecutive n -> coalesced
}

// ======== TAU2: tau[n] = 16th smallest of the 32 group-mins ========
// 16 smallest group-mins are 16 DISTINCT candidates <= tau => tau >= true d16.
// Standalone kernel at 128-VGPR cap: sort arrays stay in registers (no spill).
__global__ __launch_bounds__(256, 4) void tau2_kernel(const float* __restrict__ gsubT,
                                                      float* __restrict__ tauArr) {
    const int n = blockIdx.x * 256 + threadIdx.x;
    float A[16], B[16];
#pragma unroll
    for (int g = 0; g < 16; ++g) A[g] = gsubT[g * N_PTS + n];          // coalesced
#pragma unroll
    for (int g = 0; g < 16; ++g) B[g] = gsubT[(16 + g) * N_PTS + n];   // coalesced
    sort16f(A);
    sort16f(B);
    float tau = __uint_as_float(0xff800000u); // -inf
#pragma unroll
    for (int j = 0; j < 16; ++j) tau = fmaxf(tau, fminf(A[j], B[15 - j]));
    tauArr[n] = tau;
}

// ======== COLLECT v9: 2 queries/wave, 8 candidates/lane/iter ========
// Lane holds EIGHT candidates per iteration (eight independent coalesced
// loads in flight); tests each against 2 register-held queries. Ballot
// compaction in fixed A..H order (deterministic); rank-select order-indep.
__global__ __launch_bounds__(256, 8) void collect_kernel(const float4* __restrict__ pc,
                                                         const float* __restrict__ tauArr,
                                                         int* __restrict__ idx) {
    __shared__ u64 lists[QBLK][CAP]; // 18,432 B, wave-private pairs of rows

    const int tid  = threadIdx.x;
    const int lane = tid & 63;
    const int w    = tid >> 6;
    const int nb   = blockIdx.x * QBLK + w * QW; // first of this wave's 2 queries
    const int base = (blockIdx.x >= (HALF_N / QBLK)) ? HALF_N : 0; // block-uniform

    const float4 q0 = pc[nb + 0], q1 = pc[nb + 1];
    const float tau0 = tauArr[nb + 0], tau1 = tauArr[nb + 1];

    u64* l0 = lists[w * QW + 0];
    u64* l1 = lists[w * QW + 1];
    int c0 = 0, c1 = 0; // wave-uniform counts

    const u64 lt = (1ull << lane) - 1ull;

    for (int t0 = 0; t0 < HALF_N; t0 += 512) {
        const int ci0 = base + t0 + lane;
        float4 cp[8];
#pragma unroll
        for (int u = 0; u < 8; ++u) cp[u] = pc[ci0 + 64 * u]; // 8 loads in flight

        float d0v[8], d1v[8];
#pragma unroll
        for (int u = 0; u < 8; ++u) {
            const float4 c = cp[u];
            float dot0 = __fadd_rn(__fadd_rn(__fmul_rn(q0.x, c.x), __fmul_rn(q0.y, c.y)),
                                   __fmul_rn(q0.z, c.z));
            d0v[u] = __fsub_rn(__fadd_rn(q0.w, c.w), __fmul_rn(2.0f, dot0));
            float dot1 = __fadd_rn(__fadd_rn(__fmul_rn(q1.x, c.x), __fmul_rn(q1.y, c.y)),
                                   __fmul_rn(q1.z, c.z));
            d1v[u] = __fsub_rn(__fadd_rn(q1.w, c.w), __fmul_rn(2.0f, dot1));
        }

#define APPEND(D, TAU, LST, CNT, CI)                                                  \
        {                                                                             \
            const bool acc = !((D) > (TAU));                                          \
            const u64 mask = __ballot(acc);                                           \
            if (mask) {                                                               \
                if (acc) {                                                            \
                    int slot = (CNT) + (int)__popcll(mask & lt);                      \
                    if (slot < CAP)                                                   \
                        (LST)[slot] = ((u64)fkey(__float_as_uint(D)) << 32) | (unsigned)(CI); \
                }                                                                     \
                (CNT) += (int)__popcll(mask);                                         \
            }                                                                         \
        }
#pragma unroll
        for (int u = 0; u < 8; ++u) APPEND(d0v[u], tau0, l0, c0, ci0 + 64 * u)
#pragma unroll
        for (int u = 0; u < 8; ++u) APPEND(d1v[u], tau1, l1, c1, ci0 + 64 * u)
#undef APPEND
    }

    // rank-select per query within the wave: keys unique (idx low bits) ->
    // exact order, equal-dist -> lower index first (reference top_k semantics)
#define SELECT(LST, CNT, QI)                                                          \
    {                                                                                 \
        const int K = min((CNT), CAP);                                                \
        for (int e = lane; e < K; e += 64) {                                          \
            u64 my = (LST)[e];                                                        \
            int rank = 0;                                                             \
            for (int i = 0; i < K; ++i) rank += ((LST)[i] < my) ? 1 : 0;              \
            if (rank < 16) idx[(nb + (QI)) * KK + rank] = (int)(my & 0xffffffffULL);  \
        }                                                                             \
    }
    SELECT(l0, c0, 0)
    SELECT(l1, c1, 1)
#undef SELECT
}

// ============ per-layer conv: h once -> {part sums, raw per-point max} ============
// hbuf transposed to [tid][c] with 16B-aligned padded stride; xn-half of the
// GEMM hoisted (bit-identical fma sequence per channel).
template <int IN_C, int OUT_C, int MODE>
__global__ __launch_bounds__(256) void convS_kernel(const float* __restrict__ xin,
                                                    const float* __restrict__ statsPrev,
                                                    const int* __restrict__ idxg,
                                                    const float* __restrict__ W,
                                                    const float* __restrict__ bb,
                                                    float* __restrict__ part,
                                                    float* __restrict__ mout) {
    constexpr int RED = 256 / OUT_C;
    constexpr int HSTR = (OUT_C == 32) ? 36 : 20; // padded row stride (16B-aligned)
    __shared__ float hbuf[256][HSTR];
    __shared__ float pr1[OUT_C][RED + 1];
    __shared__ float pr2[OUT_C][RED + 1];
    __shared__ float2 sAB[IN_C];
    __shared__ float accN[16][OUT_C + 1];

    const int tid = threadIdx.x;
    const int gt = blockIdx.x * 256 + tid;
    const int n = gt >> 4;
    const int nl = tid >> 4;   // n-local 0..15
    const int kq = tid & 15;   // k within n

    if (MODE == 1) {
        if (tid < IN_C) sAB[tid] = make_float2(statsPrev[tid], statsPrev[32 + tid]);
        __syncthreads();
    }

    float xn[IN_C], dx[IN_C];
    const int j = idxg[gt];
    if (MODE == 0) {
        const float* rn = xin + n * 5 + 1;
        const float* rj = xin + j * 5 + 1;
#pragma unroll
        for (int e = 0; e < IN_C; ++e) xn[e] = rn[e];
#pragma unroll
        for (int e = 0; e < IN_C; ++e) dx[e] = rj[e] - xn[e];
    } else {
        const float4* rn = (const float4*)(xin + n * IN_C);
        const float4* rj = (const float4*)(xin + j * IN_C);
#pragma unroll
        for (int e4 = 0; e4 < IN_C / 4; ++e4) {
            float4 a = rn[e4];
            float4 bq = rj[e4];
            float av[4] = {a.x, a.y, a.z, a.w};
            float bv[4] = {bq.x, bq.y, bq.z, bq.w};
#pragma unroll
            for (int u = 0; u < 4; ++u) {
                float2 ab = sAB[4 * e4 + u];
                float xv = fmaxf(fmaf(av[u], ab.x, ab.y), 0.f);
                float jv = fmaxf(fmaf(bv[u], ab.x, ab.y), 0.f);
                xn[4 * e4 + u] = xv;
                dx[4 * e4 + u] = jv - xv;
            }
        }
    }

    // ---- owner thread computes accN for its OUT_C/16 channels ----
    {
        constexpr int CPO = OUT_C / 16;
#pragma unroll
        for (int u = 0; u < CPO; ++u) {
            const int c = kq * CPO + u;
            float acc = bb[c];
#pragma unroll
            for (int e = 0; e < IN_C; ++e) acc = fmaf(W[c * 2 * IN_C + e], xn[e], acc);
            accN[nl][c] = acc;
        }
    }
    __syncthreads();

    float h[OUT_C];
#pragma unroll
    for (int c = 0; c < OUT_C; ++c) {
        float acc = accN[nl][c]; // broadcast read (same nl across 16 lanes)
#pragma unroll
        for (int e = 0; e < IN_C; ++e) acc = fmaf(W[c * 2 * IN_C + IN_C + e], dx[e], acc);
        h[c] = acc;
    }

    // ---- vectorized store of h into transposed hbuf ----
    {
        float4* row = (float4*)&hbuf[tid][0];
#pragma unroll
        for (int c4 = 0; c4 < OUT_C / 4; ++c4)
            row[c4] = make_float4(h[4 * c4], h[4 * c4 + 1], h[4 * c4 + 2], h[4 * c4 + 3]);
    }
    __syncthreads();
    {
        const int c2 = tid & (OUT_C - 1);
        const int ch = tid / OUT_C;
        float s1 = 0.f, s2 = 0.f;
#pragma unroll
        for (int i = 0; i < OUT_C; ++i) {
            float hh = hbuf[ch * OUT_C + i][c2]; // same values, same order as before
            s1 += hh; s2 += hh * hh;
        }
        pr1[c2][ch] = s1;
        pr2[c2][ch] = s2;
    }
    __syncthreads();
    if (tid < OUT_C) {
        float t1 = 0.f, t2 = 0.f;
#pragma unroll
        for (int k = 0; k < RED; ++k) { t1 += pr1[tid][k]; t2 += pr2[tid][k]; }
        part[blockIdx.x * 64 + tid]      = t1;
        part[blockIdx.x * 64 + 32 + tid] = t2;
    }

    {
        const int n0 = blockIdx.x * 16;
        constexpr int ITER = OUT_C / 16;
#pragma unroll
        for (int r = 0; r < ITER; ++r) {
            const int c = tid & (OUT_C - 1);
            const int nl2 = (tid / OUT_C) + r * (256 / OUT_C);
            float m = hbuf[nl2 * 16][c];
#pragma unroll
            for (int k = 1; k < 16; ++k) m = fmaxf(m, hbuf[nl2 * 16 + k][c]);
            mout[(n0 + nl2) * OUT_C + c] = m;
        }
    }
}

// ======== finalize (parallel): block c reduces channel c's sum+sumsq ========
__global__ __launch_bounds__(256) void finalize_kernel(const float* __restrict__ part,
                                                       const float* __restrict__ g,
                                                       const float* __restrict__ t,
                                                       float* __restrict__ statsL) {
    __shared__ float s1[128], s2[128];
    const int c = blockIdx.x;
    const int tid = threadIdx.x;

    if (tid < 128) {
        float a = 0.f;
#pragma unroll
        for (int i = 0; i < 8; ++i) a += part[(tid * 8 + i) * 64 + c];
        s1[tid] = a;
    } else {
        const int t2 = tid - 128;
        float a = 0.f;
#pragma unroll
        for (int i = 0; i < 8; ++i) a += part[(t2 * 8 + i) * 64 + 32 + c];
        s2[t2] = a;
    }
    __syncthreads();
    for (int st = 64; st >= 1; st >>= 1) {
        if (tid < st) s1[tid] += s1[tid + st];
        else if (tid >= 128 && tid < 128 + st) s2[tid - 128] += s2[tid - 128 + st];
        __syncthreads();
    }
    if (tid == 0) {
        const float inv = 1.0f / (float)NK;
        float mu  = s1[0] * inv;
        float var = s2[0] * inv - mu * mu;
        float rs  = 1.0f / sqrtf(var + EPSV);
        float A   = rs * g[c];
        statsL[c]      = A;
        statsL[32 + c] = t[c] - mu * A;
    }
}

// ---- fused finalize(layer3) + apply: every block redundantly reduces part
// (deterministic fixed order), then applies relu(affine(m3)) to its slice ----
__global__ __launch_bounds__(256) void finapply_kernel(const float* __restrict__ part,
                                                       const float* __restrict__ g,
                                                       const float* __restrict__ t,
                                                       const float* __restrict__ m,
                                                       float* __restrict__ out) {
    __shared__ float red[4][64];
    __shared__ float tot[64];
    __shared__ float sA[32], sB[32];
    const int tid = threadIdx.x;
    const int c2 = tid & 63, ch = tid >> 6;
    float s = 0.f;
    for (int bk = ch * 256; bk < ch * 256 + 256; ++bk) s += part[bk * 64 + c2];
    red[ch][c2] = s;
    __syncthreads();
    if (tid < 64) tot[tid] = red[0][tid] + red[1][tid] + red[2][tid] + red[3][tid];
    __syncthreads();
    if (tid < 32) {
        const float inv = 1.0f / (float)NK;
        float mu  = tot[tid] * inv;
        float var = tot[32 + tid] * inv - mu * mu;
        float rs  = 1.0f / sqrtf(var + EPSV);
        float A   = rs * g[tid];
        sA[tid] = A;
        sB[tid] = t[tid] - mu * A;
    }
    __syncthreads();
    const int base = blockIdx.x * 2048 + tid;
#pragma unroll
    for (int r = 0; r < 8; ++r) {
        const int i = base + r * 256;
        float4 mv = ((const float4*)m)[i];
        const int c0 = (i * 4) & 31;
        float4 o;
        o.x = fmaxf(fmaf(mv.x, sA[c0 + 0], sB[c0 + 0]), 0.f);
        o.y = fmaxf(fmaf(mv.y, sA[c0 + 1], sB[c0 + 1]), 0.f);
        o.z = fmaxf(fmaf(mv.z, sA[c0 + 2], sB[c0 + 2]), 0.f);
        o.w = fmaxf(fmaf(mv.w, sA[c0 + 3], sB[c0 + 3]), 0.f);
        ((float4*)out)[i] = o;
    }
}

extern "C" void kernel_launch(void* const* d_in, const int* in_sizes, int n_in,
                              void* d_out, int out_size, void* d_ws, size_t ws_size,
                              hipStream_t stream) {
    const float* pts = (const float*)d_in[0];
    const float* Wl[4], *bl[4], *gl[4], *tl[4];
    for (int l = 0; l < 4; ++l) {
        Wl[l] = (const float*)d_in[1 + 4 * l + 0];
        bl[l] = (const float*)d_in[1 + 4 * l + 1];
        gl[l] = (const float*)d_in[1 + 4 * l + 2];
        tl[l] = (const float*)d_in[1 + 4 * l + 3];
    }
    char* ws = (char*)d_ws;
    int*    idx    = (int*)(ws + OFF_IDX);
    float4* pc     = (float4*)(ws + OFF_PC);
    float*  gsubT  = (float*)(ws + OFF_MA);   // 2 MB overlay (dead m0|m1)
    float*  m0     = (float*)(ws + OFF_MA);   // [N][16]
    float*  m1     = (float*)(ws + OFF_MB);   // [N][16]
    float*  m2     = (float*)(ws + OFF_MC);   // [N][32]
    float*  m3     = (float*)(ws + OFF_MA);   // [N][32] reuses MA|MB
    float*  part   = (float*)(ws + OFF_PART);
    float*  tauArr = (float*)(ws + OFF_PART); // overlay (dead until convs)
    float*  stats  = (float*)(ws + OFF_STATS);// [4][64]
    float*  out    = (float*)d_out;

    prep_kernel<<<N_PTS / 256, 256, 0, stream>>>(pts, pc);
    tau1_kernel<<<(N_PTS / 256) * TGRP, 256, 0, stream>>>(pc, gsubT);
    tau2_kernel<<<N_PTS / 256, 256, 0, stream>>>(gsubT, tauArr);
    collect_kernel<<<N_PTS / QBLK, 256, 0, stream>>>(pc, tauArr, idx);

    const int GA = NK / 256; // 1024 blocks

    // layer 0: 4 -> 16 (raw pts input)
    convS_kernel<4, 16, 0><<<GA, 256, 0, stream>>>(pts, nullptr, idx, Wl[0], bl[0], part, m0);
    finalize_kernel<<<16, 256, 0, stream>>>(part, gl[0], tl[0], stats + 0);

    // layer 1: 16 -> 16 (m0 + layer-0 affine on the fly)
    convS_kernel<16, 16, 1><<<GA, 256, 0, stream>>>(m0, stats + 0, idx, Wl[1], bl[1], part, m1);
    finalize_kernel<<<16, 256, 0, stream>>>(part, gl[1], tl[1], stats + 64);

    // layer 2: 16 -> 32
    convS_kernel<16, 32, 1><<<GA, 256, 0, stream>>>(m1, stats + 64, idx, Wl[2], bl[2], part, m2);
    finalize_kernel<<<32, 256, 0, stream>>>(part, gl[2], tl[2], stats + 128);

    // layer 3: 32 -> 32 (writes m3 over MA|MB; m0/m1 dead)
    convS_kernel<32, 32, 1><<<GA, 256, 0, stream>>>(m2, stats + 128, idx, Wl[3], bl[3], part, m3);

    // fused finalize(layer3) + out = relu(affine(m3))
    finapply_kernel<<<64, 256, 0, stream>>>(part, gl[3], tl[3], m3, out);
}

// Round 24
// 160.422 us; speedup vs baseline: 1.4498x; 1.4498x over previous
//
#include <hip/hip_runtime.h>
#include <math.h>

typedef unsigned long long u64;

#define N_PTS 16384
#define HALF_N 8192
#define KK 16
#define NK (N_PTS * KK)
#define EPSV 1e-5f
#define FINF 0x7f800000u

// ---- KNN tau phase: 32 groups x 64 candidates (subset 2048 per query) ----
#define TGRP 32                  // groups per query
#define TGC 64                   // candidates per group
// ---- KNN collect phase: 2 queries per wave, 4 candidates per lane ----
#define QW 2                     // queries per wave
#define QBLK 8                   // queries per 256-thread block
#define CAP 288                  // accept capacity (E~88, huge margin)

// ---- workspace layout (bytes) ----
#define OFF_IDX   0u                           // int32 [N_PTS][KK]         = 1 MB
#define OFF_PC    (1u << 20)                   // float4 [N_PTS]            = 256 KB
#define OFF_MA    (OFF_PC + N_PTS * 16u)       // m0 / m3 low / gsubT
#define OFF_MB    (OFF_MA + N_PTS * 16u * 4u)  // m1 / m3 high / gsubT
#define OFF_MC    (OFF_MB + N_PTS * 16u * 4u)  // m2 [N][32]                = 2 MB
#define OFF_PART  (OFF_MC + N_PTS * 32u * 4u)  // part [1024][64] / tauArr  = 256 KB
#define OFF_STATS (OFF_PART + 1024u * 64u * 4u)// float [4][64]
// gsubT (f32 [TGRP][N_PTS] = 2 MB) overlays MA|MB (dead during KNN)
// tauArr (f32 [N_PTS] = 64 KB) overlays OFF_PART (dead until conv phase)

// ---------------- prep: pack (x,y,z,d2) ----------------
__global__ __launch_bounds__(256) void prep_kernel(const float* __restrict__ pts,
                                                   float4* __restrict__ pc) {
    int i = blockIdx.x * 256 + threadIdx.x;
    float x = pts[i * 5 + 1], y = pts[i * 5 + 2], z = pts[i * 5 + 3];
    float d2 = __fadd_rn(__fadd_rn(__fmul_rn(x, x), __fmul_rn(y, y)), __fmul_rn(z, z));
    pc[i] = make_float4(x, y, z, d2);
}

// monotone key transform (float bits -> sortable uint)
__device__ __forceinline__ unsigned fkey(unsigned u) {
    return u ^ ((unsigned)(((int)u) >> 31) | 0x80000000u);
}

__device__ __forceinline__ void cef32(float& a, float& b) {
    float t = fminf(a, b);
    b = fmaxf(a, b);
    a = t;
}

// sort 8 ascending f32 (Batcher, 19 CE)
__device__ __forceinline__ void sort8f(float* b) {
    cef32(b[0], b[1]); cef32(b[2], b[3]); cef32(b[4], b[5]); cef32(b[6], b[7]);
    cef32(b[0], b[2]); cef32(b[1], b[3]); cef32(b[4], b[6]); cef32(b[5], b[7]);
    cef32(b[1], b[2]); cef32(b[5], b[6]);
    cef32(b[0], b[4]); cef32(b[1], b[5]); cef32(b[2], b[6]); cef32(b[3], b[7]);
    cef32(b[2], b[4]); cef32(b[3], b[5]);
    cef32(b[1], b[2]); cef32(b[3], b[4]); cef32(b[5], b[6]);
}

// sort 16 ascending f32: two sort8 + bitonic merge
__device__ __forceinline__ void sort16f(float b[16]) {
    sort8f(b); sort8f(b + 8);
#pragma unroll
    for (int j = 0; j < 8; ++j) cef32(b[j], b[15 - j]);
#pragma unroll
    for (int h = 0; h < 16; h += 8) {
        cef32(b[h + 0], b[h + 4]); cef32(b[h + 1], b[h + 5]);
        cef32(b[h + 2], b[h + 6]); cef32(b[h + 3], b[h + 7]);
        cef32(b[h + 0], b[h + 2]); cef32(b[h + 1], b[h + 3]);
        cef32(b[h + 4], b[h + 6]); cef32(b[h + 5], b[h + 7]);
        cef32(b[h + 0], b[h + 1]); cef32(b[h + 2], b[h + 3]);
        cef32(b[h + 4], b[h + 5]); cef32(b[h + 6], b[h + 7]);
    }
}

// ======== TAU1 v2: per (query, group) min over 64 candidates ========
// 2 block-uniform candidate loads in flight per iteration; scalar state only
// (no register arrays -> no spill risk at the 8-wave cap).
__global__ __launch_bounds__(256, 8) void tau1_kernel(const float4* __restrict__ pc,
                                                      float* __restrict__ gsubT) {
    const int qb = blockIdx.x >> 5;          // query block 0..63
    const int g  = blockIdx.x & (TGRP - 1);  // group 0..31
    const int n  = qb * 256 + threadIdx.x;
    const int base = (n >= HALF_N) ? HALF_N : 0;
    const float4 p = pc[n];

    float m = __uint_as_float(FINF);
    const int c0 = base + g * TGC; // subset = first 2048 of the batch half
#pragma unroll 4
    for (int t = 0; t < TGC; t += 2) {
        const float4 cp0 = pc[c0 + t];     // block-uniform -> broadcast, L1-hot
        const float4 cp1 = pc[c0 + t + 1]; // second load in flight
        float dot0 = __fadd_rn(__fadd_rn(__fmul_rn(p.x, cp0.x), __fmul_rn(p.y, cp0.y)),
                               __fmul_rn(p.z, cp0.z));
        float d0 = __fsub_rn(__fadd_rn(p.w, cp0.w), __fmul_rn(2.0f, dot0));
        float dot1 = __fadd_rn(__fadd_rn(__fmul_rn(p.x, cp1.x), __fmul_rn(p.y, cp1.y)),
                               __fmul_rn(p.z, cp1.z));
        float d1 = __fsub_rn(__fadd_rn(p.w, cp1.w), __fmul_rn(2.0f, dot1));
        m = fminf(fminf(m, d0), d1); // fixed order; min is exact
    }
    gsubT[g * N_PTS + n] = m; // lane-consecutive n -> coalesced
}

// ======== TAU2: tau[n] = 16th smallest of the 32 group-mins ========
// 16 smallest group-mins are 16 DISTINCT candidates <= tau => tau >= true d16.
// Standalone kernel at 128-VGPR cap: sort arrays stay in registers (no spill).
__global__ __launch_bounds__(256, 4) void tau2_kernel(const float* __restrict__ gsubT,
                                                      float* __restrict__ tauArr) {
    const int n = blockIdx.x * 256 + threadIdx.x;
    float A[16], B[16];
#pragma unroll
    for (int g = 0; g < 16; ++g) A[g] = gsubT[g * N_PTS + n];          // coalesced
#pragma unroll
    for (int g = 0; g < 16; ++g) B[g] = gsubT[(16 + g) * N_PTS + n];   // coalesced
    sort16f(A);
    sort16f(B);
    float tau = __uint_as_float(0xff800000u); // -inf
#pragma unroll
    for (int j = 0; j < 16; ++j) tau = fmaxf(tau, fminf(A[j], B[15 - j]));
    tauArr[n] = tau;
}

// ======== COLLECT v8 (r22-proven): 2 queries/wave, 4 candidates/lane/iter ========
// Lane holds FOUR candidates per iteration (four independent coalesced loads
// in flight); tests each against 2 register-held queries. Ballot compaction
// in fixed A->B->C->D order (deterministic); rank-select order-independent.
// Measured VGPR=28 -> safely under the 64-VGPR/8-wave ceiling (8-deep spills).
__global__ __launch_bounds__(256, 8) void collect_kernel(const float4* __restrict__ pc,
                                                         const float* __restrict__ tauArr,
                                                         int* __restrict__ idx) {
    __shared__ u64 lists[QBLK][CAP]; // 18,432 B, wave-private pairs of rows

    const int tid  = threadIdx.x;
    const int lane = tid & 63;
    const int w    = tid >> 6;
    const int nb   = blockIdx.x * QBLK + w * QW; // first of this wave's 2 queries
    const int base = (blockIdx.x >= (HALF_N / QBLK)) ? HALF_N : 0; // block-uniform

    const float4 q0 = pc[nb + 0], q1 = pc[nb + 1];
    const float tau0 = tauArr[nb + 0], tau1 = tauArr[nb + 1];

    u64* l0 = lists[w * QW + 0];
    u64* l1 = lists[w * QW + 1];
    int c0 = 0, c1 = 0; // wave-uniform counts

    const u64 lt = (1ull << lane) - 1ull;

    for (int t0 = 0; t0 < HALF_N; t0 += 256) {
        const int ciA = base + t0 + lane;
        const int ciB = ciA + 64;
        const int ciC = ciA + 128;
        const int ciD = ciA + 192;
        const float4 cpA = pc[ciA]; // four independent coalesced loads in flight
        const float4 cpB = pc[ciB];
        const float4 cpC = pc[ciC];
        const float4 cpD = pc[ciD];

#define DIST(Q, CP) (__fsub_rn(__fadd_rn(Q.w, CP.w), __fmul_rn(2.0f,                  \
            __fadd_rn(__fadd_rn(__fmul_rn(Q.x, CP.x), __fmul_rn(Q.y, CP.y)),          \
                      __fmul_rn(Q.z, CP.z)))))
        const float d0A = DIST(q0, cpA);
        const float d0B = DIST(q0, cpB);
        const float d0C = DIST(q0, cpC);
        const float d0D = DIST(q0, cpD);
        const float d1A = DIST(q1, cpA);
        const float d1B = DIST(q1, cpB);
        const float d1C = DIST(q1, cpC);
        const float d1D = DIST(q1, cpD);
#undef DIST

#define APPEND(D, TAU, LST, CNT, CI)                                                  \
        {                                                                             \
            const bool acc = !((D) > (TAU));                                          \
            const u64 mask = __ballot(acc);                                           \
            if (mask) {                                                               \
                if (acc) {                                                            \
                    int slot = (CNT) + (int)__popcll(mask & lt);                      \
                    if (slot < CAP)                                                   \
                        (LST)[slot] = ((u64)fkey(__float_as_uint(D)) << 32) | (unsigned)(CI); \
                }                                                                     \
                (CNT) += (int)__popcll(mask);                                         \
            }                                                                         \
        }
        APPEND(d0A, tau0, l0, c0, ciA)
        APPEND(d0B, tau0, l0, c0, ciB)
        APPEND(d0C, tau0, l0, c0, ciC)
        APPEND(d0D, tau0, l0, c0, ciD)
        APPEND(d1A, tau1, l1, c1, ciA)
        APPEND(d1B, tau1, l1, c1, ciB)
        APPEND(d1C, tau1, l1, c1, ciC)
        APPEND(d1D, tau1, l1, c1, ciD)
#undef APPEND
    }

    // rank-select per query within the wave: keys unique (idx low bits) ->
    // exact order, equal-dist -> lower index first (reference top_k semantics)
#define SELECT(LST, CNT, QI)                                                          \
    {                                                                                 \
        const int K = min((CNT), CAP);                                                \
        for (int e = lane; e < K; e += 64) {                                          \
            u64 my = (LST)[e];                                                        \
            int rank = 0;                                                             \
            for (int i = 0; i < K; ++i) rank += ((LST)[i] < my) ? 1 : 0;              \
            if (rank < 16) idx[(nb + (QI)) * KK + rank] = (int)(my & 0xffffffffULL);  \
        }                                                                             \
    }
    SELECT(l0, c0, 0)
    SELECT(l1, c1, 1)
#undef SELECT
}

// ============ per-layer conv: h once -> {part sums, raw per-point max} ============
// hbuf transposed to [tid][c] with 16B-aligned padded stride; xn-half of the
// GEMM hoisted (bit-identical fma sequence per channel).
template <int IN_C, int OUT_C, int MODE>
__global__ __launch_bounds__(256) void convS_kernel(const float* __restrict__ xin,
                                                    const float* __restrict__ statsPrev,
                                                    const int* __restrict__ idxg,
                                                    const float* __restrict__ W,
                                                    const float* __restrict__ bb,
                                                    float* __restrict__ part,
                                                    float* __restrict__ mout) {
    constexpr int RED = 256 / OUT_C;
    constexpr int HSTR = (OUT_C == 32) ? 36 : 20; // padded row stride (16B-aligned)
    __shared__ float hbuf[256][HSTR];
    __shared__ float pr1[OUT_C][RED + 1];
    __shared__ float pr2[OUT_C][RED + 1];
    __shared__ float2 sAB[IN_C];
    __shared__ float accN[16][OUT_C + 1];

    const int tid = threadIdx.x;
    const int gt = blockIdx.x * 256 + tid;
    const int n = gt >> 4;
    const int nl = tid >> 4;   // n-local 0..15
    const int kq = tid & 15;   // k within n

    if (MODE == 1) {
        if (tid < IN_C) sAB[tid] = make_float2(statsPrev[tid], statsPrev[32 + tid]);
        __syncthreads();
    }

    float xn[IN_C], dx[IN_C];
    const int j = idxg[gt];
    if (MODE == 0) {
        const float* rn = xin + n * 5 + 1;
        const float* rj = xin + j * 5 + 1;
#pragma unroll
        for (int e = 0; e < IN_C; ++e) xn[e] = rn[e];
#pragma unroll
        for (int e = 0; e < IN_C; ++e) dx[e] = rj[e] - xn[e];
    } else {
        const float4* rn = (const float4*)(xin + n * IN_C);
        const float4* rj = (const float4*)(xin + j * IN_C);
#pragma unroll
        for (int e4 = 0; e4 < IN_C / 4; ++e4) {
            float4 a = rn[e4];
            float4 bq = rj[e4];
            float av[4] = {a.x, a.y, a.z, a.w};
            float bv[4] = {bq.x, bq.y, bq.z, bq.w};
#pragma unroll
            for (int u = 0; u < 4; ++u) {
                float2 ab = sAB[4 * e4 + u];
                float xv = fmaxf(fmaf(av[u], ab.x, ab.y), 0.f);
                float jv = fmaxf(fmaf(bv[u], ab.x, ab.y), 0.f);
                xn[4 * e4 + u] = xv;
                dx[4 * e4 + u] = jv - xv;
            }
        }
    }

    // ---- owner thread computes accN for its OUT_C/16 channels ----
    {
        constexpr int CPO = OUT_C / 16;
#pragma unroll
        for (int u = 0; u < CPO; ++u) {
            const int c = kq * CPO + u;
            float acc = bb[c];
#pragma unroll
            for (int e = 0; e < IN_C; ++e) acc = fmaf(W[c * 2 * IN_C + e], xn[e], acc);
            accN[nl][c] = acc;
        }
    }
    __syncthreads();

    float h[OUT_C];
#pragma unroll
    for (int c = 0; c < OUT_C; ++c) {
        float acc = accN[nl][c]; // broadcast read (same nl across 16 lanes)
#pragma unroll
        for (int e = 0; e < IN_C; ++e) acc = fmaf(W[c * 2 * IN_C + IN_C + e], dx[e], acc);
        h[c] = acc;
    }

    // ---- vectorized store of h into transposed hbuf ----
    {
        float4* row = (float4*)&hbuf[tid][0];
#pragma unroll
        for (int c4 = 0; c4 < OUT_C / 4; ++c4)
            row[c4] = make_float4(h[4 * c4], h[4 * c4 + 1], h[4 * c4 + 2], h[4 * c4 + 3]);
    }
    __syncthreads();
    {
        const int c2 = tid & (OUT_C - 1);
        const int ch = tid / OUT_C;
        float s1 = 0.f, s2 = 0.f;
#pragma unroll
        for (int i = 0; i < OUT_C; ++i) {
            float hh = hbuf[ch * OUT_C + i][c2]; // same values, same order as before
            s1 += hh; s2 += hh * hh;
        }
        pr1[c2][ch] = s1;
        pr2[c2][ch] = s2;
    }
    __syncthreads();
    if (tid < OUT_C) {
        float t1 = 0.f, t2 = 0.f;
#pragma unroll
        for (int k = 0; k < RED; ++k) { t1 += pr1[tid][k]; t2 += pr2[tid][k]; }
        part[blockIdx.x * 64 + tid]      = t1;
        part[blockIdx.x * 64 + 32 + tid] = t2;
    }

    {
        const int n0 = blockIdx.x * 16;
        constexpr int ITER = OUT_C / 16;
#pragma unroll
        for (int r = 0; r < ITER; ++r) {
            const int c = tid & (OUT_C - 1);
            const int nl2 = (tid / OUT_C) + r * (256 / OUT_C);
            float m = hbuf[nl2 * 16][c];
#pragma unroll
            for (int k = 1; k < 16; ++k) m = fmaxf(m, hbuf[nl2 * 16 + k][c]);
            mout[(n0 + nl2) * OUT_C + c] = m;
        }
    }
}

// ======== finalize (parallel): block c reduces channel c's sum+sumsq ========
__global__ __launch_bounds__(256) void finalize_kernel(const float* __restrict__ part,
                                                       const float* __restrict__ g,
                                                       const float* __restrict__ t,
                                                       float* __restrict__ statsL) {
    __shared__ float s1[128], s2[128];
    const int c = blockIdx.x;
    const int tid = threadIdx.x;

    if (tid < 128) {
        float a = 0.f;
#pragma unroll
        for (int i = 0; i < 8; ++i) a += part[(tid * 8 + i) * 64 + c];
        s1[tid] = a;
    } else {
        const int t2 = tid - 128;
        float a = 0.f;
#pragma unroll
        for (int i = 0; i < 8; ++i) a += part[(t2 * 8 + i) * 64 + 32 + c];
        s2[t2] = a;
    }
    __syncthreads();
    for (int st = 64; st >= 1; st >>= 1) {
        if (tid < st) s1[tid] += s1[tid + st];
        else if (tid >= 128 && tid < 128 + st) s2[tid - 128] += s2[tid - 128 + st];
        __syncthreads();
    }
    if (tid == 0) {
        const float inv = 1.0f / (float)NK;
        float mu  = s1[0] * inv;
        float var = s2[0] * inv - mu * mu;
        float rs  = 1.0f / sqrtf(var + EPSV);
        float A   = rs * g[c];
        statsL[c]      = A;
        statsL[32 + c] = t[c] - mu * A;
    }
}

// ---- fused finalize(layer3) + apply: every block redundantly reduces part
// (deterministic fixed order), then applies relu(affine(m3)) to its slice ----
__global__ __launch_bounds__(256) void finapply_kernel(const float* __restrict__ part,
                                                       const float* __restrict__ g,
                                                       const float* __restrict__ t,
                                                       const float* __restrict__ m,
                                                       float* __restrict__ out) {
    __shared__ float red[4][64];
    __shared__ float tot[64];
    __shared__ float sA[32], sB[32];
    const int tid = threadIdx.x;
    const int c2 = tid & 63, ch = tid >> 6;
    float s = 0.f;
    for (int bk = ch * 256; bk < ch * 256 + 256; ++bk) s += part[bk * 64 + c2];
    red[ch][c2] = s;
    __syncthreads();
    if (tid < 64) tot[tid] = red[0][tid] + red[1][tid] + red[2][tid] + red[3][tid];
    __syncthreads();
    if (tid < 32) {
        const float inv = 1.0f / (float)NK;
        float mu  = tot[tid] * inv;
        float var = tot[32 + tid] * inv - mu * mu;
        float rs  = 1.0f / sqrtf(var + EPSV);
        float A   = rs * g[tid];
        sA[tid] = A;
        sB[tid] = t[tid] - mu * A;
    }
    __syncthreads();
    const int base = blockIdx.x * 2048 + tid;
#pragma unroll
    for (int r = 0; r < 8; ++r) {
        const int i = base + r * 256;
        float4 mv = ((const float4*)m)[i];
        const int c0 = (i * 4) & 31;
        float4 o;
        o.x = fmaxf(fmaf(mv.x, sA[c0 + 0], sB[c0 + 0]), 0.f);
        o.y = fmaxf(fmaf(mv.y, sA[c0 + 1], sB[c0 + 1]), 0.f);
        o.z = fmaxf(fmaf(mv.z, sA[c0 + 2], sB[c0 + 2]), 0.f);
        o.w = fmaxf(fmaf(mv.w, sA[c0 + 3], sB[c0 + 3]), 0.f);
        ((float4*)out)[i] = o;
    }
}

extern "C" void kernel_launch(void* const* d_in, const int* in_sizes, int n_in,
                              void* d_out, int out_size, void* d_ws, size_t ws_size,
                              hipStream_t stream) {
    const float* pts = (const float*)d_in[0];
    const float* Wl[4], *bl[4], *gl[4], *tl[4];
    for (int l = 0; l < 4; ++l) {
        Wl[l] = (const float*)d_in[1 + 4 * l + 0];
        bl[l] = (const float*)d_in[1 + 4 * l + 1];
        gl[l] = (const float*)d_in[1 + 4 * l + 2];
        tl[l] = (const float*)d_in[1 + 4 * l + 3];
    }
    char* ws = (char*)d_ws;
    int*    idx    = (int*)(ws + OFF_IDX);
    float4* pc     = (float4*)(ws + OFF_PC);
    float*  gsubT  = (float*)(ws + OFF_MA);   // 2 MB overlay (dead m0|m1)
    float*  m0     = (float*)(ws + OFF_MA);   // [N][16]
    float*  m1     = (float*)(ws + OFF_MB);   // [N][16]
    float*  m2     = (float*)(ws + OFF_MC);   // [N][32]
    float*  m3     = (float*)(ws + OFF_MA);   // [N][32] reuses MA|MB
    float*  part   = (float*)(ws + OFF_PART);
    float*  tauArr = (float*)(ws + OFF_PART); // overlay (dead until convs)
    float*  stats  = (float*)(ws + OFF_STATS);// [4][64]
    float*  out    = (float*)d_out;

    prep_kernel<<<N_PTS / 256, 256, 0, stream>>>(pts, pc);
    tau1_kernel<<<(N_PTS / 256) * TGRP, 256, 0, stream>>>(pc, gsubT);
    tau2_kernel<<<N_PTS / 256, 256, 0, stream>>>(gsubT, tauArr);
    collect_kernel<<<N_PTS / QBLK, 256, 0, stream>>>(pc, tauArr, idx);

    const int GA = NK / 256; // 1024 blocks

    // layer 0: 4 -> 16 (raw pts input)
    convS_kernel<4, 16, 0><<<GA, 256, 0, stream>>>(pts, nullptr, idx, Wl[0], bl[0], part, m0);
    finalize_kernel<<<16, 256, 0, stream>>>(part, gl[0], tl[0], stats + 0);

    // layer 1: 16 -> 16 (m0 + layer-0 affine on the fly)
    convS_kernel<16, 16, 1><<<GA, 256, 0, stream>>>(m0, stats + 0, idx, Wl[1], bl[1], part, m1);
    finalize_kernel<<<16, 256, 0, stream>>>(part, gl[1], tl[1], stats + 64);

    // layer 2: 16 -> 32
    convS_kernel<16, 32, 1><<<GA, 256, 0, stream>>>(m1, stats + 64, idx, Wl[2], bl[2], part, m2);
    finalize_kernel<<<32, 256, 0, stream>>>(part, gl[2], tl[2], stats + 128);

    // layer 3: 32 -> 32 (writes m3 over MA|MB; m0/m1 dead)
    convS_kernel<32, 32, 1><<<GA, 256, 0, stream>>>(m2, stats + 128, idx, Wl[3], bl[3], part, m3);

    // fused finalize(layer3) + out = relu(affine(m3))
    finapply_kernel<<<64, 256, 0, stream>>>(part, gl[3], tl[3], m3, out);
}